// Round 4
// baseline (2948.116 us; speedup 1.0000x reference)
//
#include <hip/hip_runtime.h>
#include <hip/hip_bf16.h>

// LSNN adaptive-LIF scan, T=1000, B=64, N_in=256, N_h=512, fp32.
//
// BITWISE CONSTRAINT (rounds 2-5): harness compares binary spikes exactly;
// flips cascade. numpy/OpenBLAS reduces k sequentially ascending, so the
// recurrent term for column n MUST be one serial ascending-index __fadd_rn
// chain over active neurons. No partial sums. Pad rows add +0.0 (bitwise
// neutral). Verified absmax 0 across rounds.
//
// Round 11: r7/r8/r9/r10 (three different latency-pipelining structures)
// all land at 2422-2600us -> NOT latency-bound. Revised model: per-CU
// memory-pipe THROUGHPUT. One WG per batch = 64 CUs active; gather moves
// cnt x 2KB per step through one CU at ~60-64 B/cy (L1 inbound / TA addr
// rate) -> cnt~180 gives ~5800 cy/step = measured. Fix: split each batch's
// 512 columns over 4 WGs x 128 threads (256 WGs on 256 CUs, per-CU traffic
// /4). Serial chain per column untouched (one thread owns one column ->
// bitwise identical). Cross-WG spike-mask exchange per step via tag-carrying
// packed u64 atomics (hi32 = step code, lo32 = 32-bit half-mask): freshness
// self-verified -> RELAXED device-scope atomics only, no fences, no
// vmcnt(0)-before-release stalls. Group {b,b+64,b+128,b+192} -> same XCD
// under %8 round-robin (64%8==0), so spins are L2-local; correctness does
// not depend on placement. Ring=4 slots; max skew between group mates is 1
// step (publish precedes spin). Gather = round-7 fill_tile form (best
// measured; PIN16/decoupling dropped as neutral-to-harmful).

#define TT   1000
#define BB   64
#define NIN  256
#define NH   512
#define TS   16                          // gather tile size (mult of 4)
#define LPAD (4 * TS)                    // list pad region
#define PADOFF (NH * 2048)               // byte offset of zeroed row 512 of wT
#define NW   4                           // WGs per batch (column split)
#define WCOLS (NH / NW)                  // 128 columns per WG
#define RING 4                           // mask ring slots

__device__ constexpr float KV = (float)(0.001 * 100.0);            // DT*TAU_MEM_INV
__device__ constexpr float KI = (float)(0.001 * 200.0);            // DT*TAU_SYN_INV
__device__ constexpr float KB = (float)(0.001 * (1.0 / 800.0));    // DT*TAU_ADAPT_INV
__device__ constexpr float KJ = (float)((1.0 / 800.0) * 1.8);      // TAU_ADAPT_INV*BETA

// ---------------- transpose w_rec (512x512): wT[j][n] = w_rec[n][j] ----------
__global__ void transp512(const float* __restrict__ in, float* __restrict__ ot) {
    __shared__ float tile[32][33];
    const int tx = threadIdx.x;            // 0..31
    const int ty = threadIdx.y;            // 0..7
    const int jcol = blockIdx.x * 32 + tx;
    const int row0 = blockIdx.y * 32;
    for (int r = ty; r < 32; r += 8)
        tile[r][tx] = in[(size_t)(row0 + r) * NH + jcol];
    __syncthreads();
    const int ncol = blockIdx.y * 32 + tx;
    const int jrow0 = blockIdx.x * 32;
    for (int r = ty; r < 32; r += 8)
        ot[(size_t)(jrow0 + r) * NH + ncol] = tile[tx][r];
}

// zero row 512 of wT (padding target for unconditional gather tiles)
__global__ void zrow(float* __restrict__ wT) {
    wT[(size_t)NH * NH + threadIdx.x] = 0.0f;
}

// zero the mask ring (tag 0 = invalid; published codes are >= 1)
__global__ void zmask(unsigned long long* __restrict__ gm) {
    for (int k = threadIdx.x; k < RING * BB * 16; k += 256) gm[k] = 0ull;
}

// ---------------- fp32 GEMM: F[m][n] = sum_k X[m][k] * W[n][k] ---------------
// UNCHANGED from round 2 (bitwise-verified against the np reference).
__global__ __launch_bounds__(256)
void gemm_ff(const float* __restrict__ X, const float* __restrict__ W,
             float* __restrict__ F, int M) {
    const int bx = blockIdx.x;   // n-tile: 0..3
    const int by = blockIdx.y;   // m-tile
    const int tid = threadIdx.x;

    __shared__ float As[32][128];
    __shared__ float Bs[32][128];

    const int tn0 = (tid & 15) * 8;
    const int tm0 = (tid >> 4) * 8;
    float acc[8][8] = {};

    const int am = tid >> 1;
    const int aq = (tid & 1) * 4;

    const float* Xb = X + (size_t)(by * 128 + am) * NIN;
    const float* Wb = W + (size_t)(bx * 128 + am) * NIN;

    for (int k0 = 0; k0 < NIN; k0 += 32) {
        __syncthreads();
#pragma unroll
        for (int i2 = 0; i2 < 4; ++i2) {
            const int q = aq + i2;
            float4 xa = *reinterpret_cast<const float4*>(Xb + k0 + q * 4);
            As[q * 4 + 0][am] = xa.x; As[q * 4 + 1][am] = xa.y;
            As[q * 4 + 2][am] = xa.z; As[q * 4 + 3][am] = xa.w;
            float4 wa = *reinterpret_cast<const float4*>(Wb + k0 + q * 4);
            Bs[q * 4 + 0][am] = wa.x; Bs[q * 4 + 1][am] = wa.y;
            Bs[q * 4 + 2][am] = wa.z; Bs[q * 4 + 3][am] = wa.w;
        }
        __syncthreads();
#pragma unroll 8
        for (int kk = 0; kk < 32; ++kk) {
            float4 a0 = *reinterpret_cast<const float4*>(&As[kk][tm0]);
            float4 a1 = *reinterpret_cast<const float4*>(&As[kk][tm0 + 4]);
            float4 b0 = *reinterpret_cast<const float4*>(&Bs[kk][tn0]);
            float4 b1 = *reinterpret_cast<const float4*>(&Bs[kk][tn0 + 4]);
            const float av[8] = {a0.x, a0.y, a0.z, a0.w, a1.x, a1.y, a1.z, a1.w};
            const float bv[8] = {b0.x, b0.y, b0.z, b0.w, b1.x, b1.y, b1.z, b1.w};
#pragma unroll
            for (int i = 0; i < 8; ++i)
#pragma unroll
                for (int j = 0; j < 8; ++j)
                    acc[i][j] += av[i] * bv[j];
        }
    }

    float* Fo = F + (size_t)(by * 128 + tm0) * NH + bx * 128 + tn0;
#pragma unroll
    for (int i = 0; i < 8; ++i) {
        *reinterpret_cast<float4*>(Fo + (size_t)i * NH) =
            make_float4(acc[i][0], acc[i][1], acc[i][2], acc[i][3]);
        *reinterpret_cast<float4*>(Fo + (size_t)i * NH + 4) =
            make_float4(acc[i][4], acc[i][5], acc[i][6], acc[i][7]);
    }
}

// ---------------- gather helpers (round-7 form: best measured) ---------------
__device__ __forceinline__ void fill_tile(float (&buf)[TS], const int* lp,
                                          int base, const char* wb,
                                          unsigned n4) {
#pragma unroll
    for (int i = 0; i < TS; i += 4) {
        const int4 o = *reinterpret_cast<const int4*>(lp + base + i);
        buf[i + 0] = *reinterpret_cast<const float*>(wb + (unsigned)(o.x + (int)n4));
        buf[i + 1] = *reinterpret_cast<const float*>(wb + (unsigned)(o.y + (int)n4));
        buf[i + 2] = *reinterpret_cast<const float*>(wb + (unsigned)(o.z + (int)n4));
        buf[i + 3] = *reinterpret_cast<const float*>(wb + (unsigned)(o.w + (int)n4));
    }
}
__device__ __forceinline__ void add_tile(const float (&buf)[TS], float& rec) {
#pragma unroll
    for (int i = 0; i < TS; ++i) rec = __fadd_rn(rec, buf[i]);
}

// ---------------- scan kernel: 4 WGs x 128 threads per batch ----------------
// blockIdx = b + 64*s  (groups of a batch land on one XCD under %8 RR).
// st layout: [z | v | i | b], each BB*NH floats.
// gmask[slot][b][w16]: packed u64, hi32 = step-code (stepFed+1), lo32 =
// 32-neuron half-mask. w16 = neuron/32, ascending.
__global__ __launch_bounds__(WCOLS, 1)
void lsnn_scan(const float* __restrict__ F, const float* __restrict__ wT,
               const float* __restrict__ z0, const float* __restrict__ v0,
               const float* __restrict__ i0, const float* __restrict__ b0,
               float* __restrict__ out, float* __restrict__ st,
               unsigned long long* __restrict__ gmask,
               int t0, int Tc, int first, int last) {
    const int tid  = threadIdx.x;              // 0..127
    const int b    = blockIdx.x & (BB - 1);    // batch
    const int s    = blockIdx.x >> 6;          // column group 0..3
    const int lane = tid & 63;
    const int wv   = tid >> 6;                 // wave 0..1
    const int c    = s * WCOLS + tid;          // global column
    const size_t bn = (size_t)b * NH + c;

    __shared__ __align__(16) int list_[NH + LPAD];
    __shared__ unsigned smask32[16];

    float v, cur, bb, zprev;
    if (first) {
        zprev = z0[bn]; v = v0[bn]; cur = i0[bn]; bb = b0[bn];
    } else {
        zprev = st[0 * BB * NH + bn];
        v     = st[1 * BB * NH + bn];
        cur   = st[2 * BB * NH + bn];
        bb    = st[3 * BB * NH + bn];
    }

    // ---- entry publish: zprev half-masks, code t0+1 (feeds step t0) --------
    {
        const unsigned long long m0 = __ballot(zprev > 0.0f);
        if (lane == 0) {
            const size_t gi = (((size_t)((unsigned)t0 & (RING - 1)) * BB + b) << 4)
                              + ((unsigned)(2 * s + wv) << 1);
            const unsigned long long code = (unsigned long long)(unsigned)(t0 + 1) << 32;
            __hip_atomic_store(&gmask[gi],     code | (unsigned)(m0 & 0xffffffffull),
                               __ATOMIC_RELAXED, __HIP_MEMORY_SCOPE_AGENT);
            __hip_atomic_store(&gmask[gi + 1], code | (unsigned)(m0 >> 32),
                               __ATOMIC_RELAXED, __HIP_MEMORY_SCOPE_AGENT);
        }
    }

    const char*  wb = reinterpret_cast<const char*>(wT);   // uniform base (SGPR)
    const unsigned n4 = (unsigned)c * 4u;                  // column byte offset
    const float* Fp = F + (size_t)b * NH + c;
    float* op = out + ((size_t)t0 * BB + b) * NH + c;

    for (int t = 0; t < Tc; ++t) {
        const unsigned T = (unsigned)(t0 + t);

        // ---- A: elementwise update (carried v, cur, bb), ballot, publish ----
        const float v_dec = __fadd_rn(v, __fmul_rn(KV, __fadd_rn(__fsub_rn(0.0f, v), cur)));
        const float i_dec = __fsub_rn(cur, __fmul_rn(KI, cur));
        const float b_dec = __fadd_rn(bb, __fmul_rn(KB, __fsub_rn(1.0f, bb)));
        const float zn = (__fsub_rn(v_dec, b_dec) > 0.0f) ? 1.0f : 0.0f;
        v  = (zn > 0.0f) ? 0.0f : v_dec;
        bb = __fadd_rn(b_dec, __fmul_rn(zn, KJ));
        const unsigned long long mm = __ballot(zn > 0.0f);
        if (lane == 0) {
            // mask feeding step T+1 -> code T+2, slot (T+1)&3
            const size_t gi = (((size_t)((T + 1u) & (RING - 1)) * BB + b) << 4)
                              + ((unsigned)(2 * s + wv) << 1);
            const unsigned long long code = (unsigned long long)(T + 2u) << 32;
            __hip_atomic_store(&gmask[gi],     code | (unsigned)(mm & 0xffffffffull),
                               __ATOMIC_RELAXED, __HIP_MEMORY_SCOPE_AGENT);
            __hip_atomic_store(&gmask[gi + 1], code | (unsigned)(mm >> 32),
                               __ATOMIC_RELAXED, __HIP_MEMORY_SCOPE_AGENT);
        }

        // ---- C: acquire all 16 half-masks feeding step T (code T+1) --------
        if (tid < 16) {
            const size_t gi = (((size_t)(T & (RING - 1)) * BB + b) << 4) + tid;
            unsigned long long x;
            do {
                x = __hip_atomic_load(&gmask[gi], __ATOMIC_RELAXED,
                                      __HIP_MEMORY_SCOPE_AGENT);
            } while ((unsigned)(x >> 32) != T + 1u);
            smask32[tid] = (unsigned)x;
        }
        __syncthreads();   // D: masks in LDS

        // ---- E: build ascending row-offset list -----------------------------
        unsigned long long w8[8];
        int bases[8];
        int run = 0;
#pragma unroll
        for (int w = 0; w < 8; ++w) {
            w8[w] = (unsigned long long)smask32[2 * w]
                  | ((unsigned long long)smask32[2 * w + 1] << 32);
            bases[w] = run;
            run += __popcll(w8[w]);
        }
        const int cnt = run;
#pragma unroll
        for (int q = 0; q < 4; ++q) {
            const int w = wv * 4 + q;
            const unsigned long long m = w8[w];
            if ((m >> lane) & 1ull)
                list_[bases[w] + __popcll(m & ((1ull << lane) - 1ull))]
                    = (w * 64 + lane) << 11;
        }
        if (tid < LPAD) list_[cnt + tid] = PADOFF;
        __syncthreads();   // Fb: list ready (last barrier before loads)

        // ---- G: out store + F prefetch + pipelined serial gather ------------
        op[0] = zn;
        op += (size_t)BB * NH;
        const float fval = Fp[(size_t)t * BB * NH];   // consumed after gather
        float rec = 0.0f;
        if (cnt > 0) {
            const int* lp = list_;
            float bufA[TS], bufB[TS];
            fill_tile(bufA, lp, 0, wb, n4);
            __builtin_amdgcn_sched_barrier(0);
            int kt = 0;
            for (;;) {
                fill_tile(bufB, lp, kt + TS, wb, n4);   // next tile in flight
                __builtin_amdgcn_sched_barrier(0);
                add_tile(bufA, rec);                    // chain current tile
                kt += TS;
                if (kt >= cnt) break;
                fill_tile(bufA, lp, kt + TS, wb, n4);
                __builtin_amdgcn_sched_barrier(0);
                add_tile(bufB, rec);
                kt += TS;
                if (kt >= cnt) break;
            }
        }
        cur = __fadd_rn(__fadd_rn(i_dec, fval), rec);
        zprev = zn;
    }

    st[0 * BB * NH + bn] = zprev;
    st[1 * BB * NH + bn] = v;
    st[2 * BB * NH + bn] = cur;
    st[3 * BB * NH + bn] = bb;
    if (last) {
        float* tail = out + (size_t)TT * BB * NH;
        tail[0 * BB * NH + bn] = zprev;  // zT
        tail[1 * BB * NH + bn] = v;      // vT
        tail[2 * BB * NH + bn] = cur;    // iT
        tail[3 * BB * NH + bn] = bb;     // bT
    }
}

// ---------------------------------------------------------------------------
extern "C" void kernel_launch(void* const* d_in, const int* in_sizes, int n_in,
                              void* d_out, int out_size, void* d_ws, size_t ws_size,
                              hipStream_t stream) {
    const float* X     = (const float*)d_in[0];
    const float* z0    = (const float*)d_in[1];
    const float* v0    = (const float*)d_in[2];
    const float* i0    = (const float*)d_in[3];
    const float* b0    = (const float*)d_in[4];
    const float* w_in  = (const float*)d_in[5];
    const float* w_rec = (const float*)d_in[6];
    float* out = (float*)d_out;

    char* ws = (char*)d_ws;
    float* wT = (float*)ws;                                    // 1 MB + zero row
    const size_t wT_bytes = ((size_t)NH * NH + NH) * 4 + 2048;
    float* st = (float*)(ws + wT_bytes);                       // 512 KB
    const size_t mask_bytes = (size_t)RING * BB * 16 * 8;      // 32 KB
    unsigned long long* gmask =
        (unsigned long long*)(ws + wT_bytes + (512u << 10));
    char* fbase = ws + wT_bytes + (512u << 10) + mask_bytes;

    const long long per = (long long)BB * NH * 4;              // bytes/step of F
    long long avail = (long long)ws_size
                    - (long long)(wT_bytes + (512u << 10) + mask_bytes);
    int Tc;
    if (avail >= 2 * per * TT) {
        Tc = TT;
    } else {
        Tc = (int)(avail / (2 * per));
        if (Tc > TT) Tc = TT;
        Tc &= ~1;
        if (Tc < 2) Tc = 2;
    }
    const size_t fbytes = (size_t)Tc * per;
    float* Fb[2] = { (float*)fbase, (float*)(fbase + fbytes) };

    transp512<<<dim3(16, 16), dim3(32, 8), 0, stream>>>(w_rec, wT);
    zrow<<<1, NH, 0, stream>>>(wT);
    zmask<<<1, 256, 0, stream>>>(gmask);

    int t0 = 0, buf = 0;
    bool firstc = true;
    while (t0 < TT) {
        const int Tcur = (Tc < TT - t0) ? Tc : (TT - t0);
        const int Mc = Tcur * BB;
        gemm_ff<<<dim3(4, Mc / 128), 256, 0, stream>>>(
            X + (size_t)t0 * BB * NIN, w_in, Fb[buf], Mc);
        lsnn_scan<<<dim3(BB * NW), dim3(WCOLS), 0, stream>>>(
            Fb[buf], wT, z0, v0, i0, b0, out, st, gmask,
            t0, Tcur, firstc ? 1 : 0, (t0 + Tcur >= TT) ? 1 : 0);
        firstc = false;
        buf ^= 1;
        t0 += Tcur;
    }
}

// Round 5
// 2909.898 us; speedup vs baseline: 1.0131x; 1.0131x over previous
//
#include <hip/hip_runtime.h>
#include <hip/hip_bf16.h>

// LSNN adaptive-LIF scan, T=1000, B=64, N_in=256, N_h=512, fp32.
//
// BITWISE CONSTRAINT (rounds 2-5): harness compares binary spikes exactly;
// flips cascade. numpy/OpenBLAS reduces k sequentially ascending, so the
// recurrent term for column n MUST be one serial ascending-index __fadd_rn
// chain over active neurons. No partial sums. Pad rows (+0.0 from zeroed
// row 512) are bitwise neutral. Verified absmax 0 across rounds.
//
// Round 12: r7-r11 invariant explained: time/step = cnt * L2_lat / inflight,
// and the compiler ALWAYS re-rolled the gather to ~4 loads in flight
// (VGPR 36-48 in every variant), regardless of topology (total waves fixed
// at 512, so spreading over CUs changes nothing). All source-level hints
// (sched_barrier, PIN, decoupled buffers) failed to change machine-level
// in-flight depth. Fix: the gather inner loop is RAW INLINE ASM with fixed
// physical registers: 2x16-element data tiles in flight (v116-v147),
// offsets ds_read 2 tiles ahead (v84-v115), explicit counted
// s_waitcnt vmcnt(16) before each 16-add ascending chain, internal loop,
// final vmcnt(0) drain. Ascending serial add chain preserved exactly;
// consumed count rounded up to 32 with +0.0 pads (uniform, branchless).
// Topology = r7 (64 WGs x 512 thr, no cross-WG protocol).

#define TT   1000
#define BB   64
#define NIN  256
#define NH   512
#define TS   16
#define LPAD (4 * TS)                    // pads cover cnt+47 max read index
#define PADOFF (NH * 2048)               // byte offset of zeroed row 512 of wT

__device__ constexpr float KV = (float)(0.001 * 100.0);            // DT*TAU_MEM_INV
__device__ constexpr float KI = (float)(0.001 * 200.0);            // DT*TAU_SYN_INV
__device__ constexpr float KB = (float)(0.001 * (1.0 / 800.0));    // DT*TAU_ADAPT_INV
__device__ constexpr float KJ = (float)((1.0 / 800.0) * 1.8);      // TAU_ADAPT_INV*BETA

// ---------------- transpose w_rec (512x512): wT[j][n] = w_rec[n][j] ----------
__global__ void transp512(const float* __restrict__ in, float* __restrict__ ot) {
    __shared__ float tile[32][33];
    const int tx = threadIdx.x;            // 0..31
    const int ty = threadIdx.y;            // 0..7
    const int jcol = blockIdx.x * 32 + tx;
    const int row0 = blockIdx.y * 32;
    for (int r = ty; r < 32; r += 8)
        tile[r][tx] = in[(size_t)(row0 + r) * NH + jcol];
    __syncthreads();
    const int ncol = blockIdx.y * 32 + tx;
    const int jrow0 = blockIdx.x * 32;
    for (int r = ty; r < 32; r += 8)
        ot[(size_t)(jrow0 + r) * NH + ncol] = tile[tx][r];
}

// zero row 512 of wT (padding target for unconditional gather tiles)
__global__ void zrow(float* __restrict__ wT) {
    wT[(size_t)NH * NH + threadIdx.x] = 0.0f;
}

// ---------------- fp32 GEMM: F[m][n] = sum_k X[m][k] * W[n][k] ---------------
// UNCHANGED from round 2 (bitwise-verified against the np reference).
__global__ __launch_bounds__(256)
void gemm_ff(const float* __restrict__ X, const float* __restrict__ W,
             float* __restrict__ F, int M) {
    const int bx = blockIdx.x;   // n-tile: 0..3
    const int by = blockIdx.y;   // m-tile
    const int tid = threadIdx.x;

    __shared__ float As[32][128];
    __shared__ float Bs[32][128];

    const int tn0 = (tid & 15) * 8;
    const int tm0 = (tid >> 4) * 8;
    float acc[8][8] = {};

    const int am = tid >> 1;
    const int aq = (tid & 1) * 4;

    const float* Xb = X + (size_t)(by * 128 + am) * NIN;
    const float* Wb = W + (size_t)(bx * 128 + am) * NIN;

    for (int k0 = 0; k0 < NIN; k0 += 32) {
        __syncthreads();
#pragma unroll
        for (int i2 = 0; i2 < 4; ++i2) {
            const int q = aq + i2;
            float4 xa = *reinterpret_cast<const float4*>(Xb + k0 + q * 4);
            As[q * 4 + 0][am] = xa.x; As[q * 4 + 1][am] = xa.y;
            As[q * 4 + 2][am] = xa.z; As[q * 4 + 3][am] = xa.w;
            float4 wa = *reinterpret_cast<const float4*>(Wb + k0 + q * 4);
            Bs[q * 4 + 0][am] = wa.x; Bs[q * 4 + 1][am] = wa.y;
            Bs[q * 4 + 2][am] = wa.z; Bs[q * 4 + 3][am] = wa.w;
        }
        __syncthreads();
#pragma unroll 8
        for (int kk = 0; kk < 32; ++kk) {
            float4 a0 = *reinterpret_cast<const float4*>(&As[kk][tm0]);
            float4 a1 = *reinterpret_cast<const float4*>(&As[kk][tm0 + 4]);
            float4 b0 = *reinterpret_cast<const float4*>(&Bs[kk][tn0]);
            float4 b1 = *reinterpret_cast<const float4*>(&Bs[kk][tn0 + 4]);
            const float av[8] = {a0.x, a0.y, a0.z, a0.w, a1.x, a1.y, a1.z, a1.w};
            const float bv[8] = {b0.x, b0.y, b0.z, b0.w, b1.x, b1.y, b1.z, b1.w};
#pragma unroll
            for (int i = 0; i < 8; ++i)
#pragma unroll
                for (int j = 0; j < 8; ++j)
                    acc[i][j] += av[i] * bv[j];
        }
    }

    float* Fo = F + (size_t)(by * 128 + tm0) * NH + bx * 128 + tn0;
#pragma unroll
    for (int i = 0; i < 8; ++i) {
        *reinterpret_cast<float4*>(Fo + (size_t)i * NH) =
            make_float4(acc[i][0], acc[i][1], acc[i][2], acc[i][3]);
        *reinterpret_cast<float4*>(Fo + (size_t)i * NH + 4) =
            make_float4(acc[i][4], acc[i][5], acc[i][6], acc[i][7]);
    }
}

// ---------------- asm gather building blocks --------------------------------
// GLD: compute address (row byte offset + column byte offset) and issue load.
// Address reg v82 is sampled at VMEM issue, safe to reuse immediately.
#define GLD(o, d) \
    "v_add_u32 v82, %[n4], " o "\n\t" \
    "global_load_dword " d ", v82, %[wb]\n\t"
// ADDF: one link of the ascending serial chain (bitwise-mandated order).
#define ADDF(s) "v_add_f32 %[rec], %[rec], " s "\n\t"

// ---------------- scan kernel: one WG (512 thr) per batch element -----------
// st layout: [z | v | i | b], each BB*NH floats.
__global__ __launch_bounds__(512, 1)
void lsnn_scan(const float* __restrict__ F, const float* __restrict__ wT,
               const float* __restrict__ z0, const float* __restrict__ v0,
               const float* __restrict__ i0, const float* __restrict__ b0,
               float* __restrict__ out, float* __restrict__ st,
               int t0, int Tc, int first, int last) {
    const int n    = threadIdx.x;        // neuron / column 0..511
    const int b    = blockIdx.x;         // batch
    const int lane = n & 63;
    const int wv   = n >> 6;             // wave 0..7
    const size_t bn = (size_t)b * NH + n;

    __shared__ __align__(16) int lists[2][NH + LPAD];  // row byte offsets + pad
    __shared__ int cnts[2][8];

    float v, cur, bb, zprev;
    if (first) {
        zprev = z0[bn]; v = v0[bn]; cur = i0[bn]; bb = b0[bn];
    } else {
        zprev = st[0 * BB * NH + bn];
        v     = st[1 * BB * NH + bn];
        cur   = st[2 * BB * NH + bn];
        bb    = st[3 * BB * NH + bn];
    }

    // ---- initial list build (buffer 0), ascending neuron order -------------
    int cnt;
    {
        const unsigned long long m = __ballot(zprev > 0.0f);
        if (lane == 0) cnts[0][wv] = __popcll(m);
        __syncthreads();
        int base = 0, tot = 0;
        for (int q = 0; q < 8; ++q) {
            const int c = cnts[0][q];
            if (q < wv) base += c;
            tot += c;
        }
        if (zprev > 0.0f)
            lists[0][base + __popcll(m & ((1ull << lane) - 1ull))] = n << 11;
        if (n < LPAD) lists[0][tot + n] = PADOFF;   // pad region
        __syncthreads();
        cnt = tot;
    }
    int par = 0;

    const char*  wb = reinterpret_cast<const char*>(wT);   // uniform base (SGPR)
    const unsigned n4 = (unsigned)n * 4u;                  // column byte offset
    const float* Fp = F + (size_t)b * NH + n;
    float* op = out + ((size_t)t0 * BB + b) * NH + n;

    for (int t = 0; t < Tc; ++t) {
        // ---- t.1: elementwise update, ballot, publish next counts ----------
        const float v_dec = __fadd_rn(v, __fmul_rn(KV, __fadd_rn(__fsub_rn(0.0f, v), cur)));
        const float i_dec = __fsub_rn(cur, __fmul_rn(KI, cur));
        const float b_dec = __fadd_rn(bb, __fmul_rn(KB, __fsub_rn(1.0f, bb)));
        const float zn = (__fsub_rn(v_dec, b_dec) > 0.0f) ? 1.0f : 0.0f;
        v  = (zn > 0.0f) ? 0.0f : v_dec;
        bb = __fadd_rn(b_dec, __fmul_rn(zn, KJ));
        const unsigned long long mm = __ballot(zn > 0.0f);
        if (lane == 0) cnts[par ^ 1][wv] = __popcll(mm);

        // ---- t.2: F prefetch (hidden under the asm gather) + asm gather ----
        // The volatile asm below is a scheduling fence: the fval load cannot
        // sink past it, so its L2/L3 latency hides under the gather.
        const float fval = Fp[(size_t)t * BB * NH];

        float rec = 0.0f;
        {
            const unsigned lds_off =
                (unsigned)(unsigned long long)(const void*)lists[par];
            // 2-tile (16-elem) software pipeline, all in one asm block:
            //   prologue: offs(0) -> issue tile0 -> A
            //   loop:     offs(k+1,k+2); issue k+1 -> B; vmcnt(16); add A;
            //             issue k+2 -> A; vmcnt(16); add B; rem -= 32
            //   epilogue: vmcnt(0) drain (clobbered regs must be quiescent)
            // Consumes ceil(cnt/32)*32 entries (pads are +0.0, bitwise-safe).
            asm volatile(
                "v_mov_b32 v80, %[lds]\n\t"
                "v_mov_b32 v81, %[cnt]\n\t"
                "ds_read_b128 v[84:87], v80\n\t"
                "ds_read_b128 v[88:91], v80 offset:16\n\t"
                "ds_read_b128 v[92:95], v80 offset:32\n\t"
                "ds_read_b128 v[96:99], v80 offset:48\n\t"
                "v_add_u32 v80, 64, v80\n\t"
                "s_waitcnt lgkmcnt(0)\n\t"
                GLD("v84", "v116") GLD("v85", "v117")
                GLD("v86", "v118") GLD("v87", "v119")
                GLD("v88", "v120") GLD("v89", "v121")
                GLD("v90", "v122") GLD("v91", "v123")
                GLD("v92", "v124") GLD("v93", "v125")
                GLD("v94", "v126") GLD("v95", "v127")
                GLD("v96", "v128") GLD("v97", "v129")
                GLD("v98", "v130") GLD("v99", "v131")
                "Lg%=:\n\t"
                "ds_read_b128 v[84:87], v80\n\t"
                "ds_read_b128 v[88:91], v80 offset:16\n\t"
                "ds_read_b128 v[92:95], v80 offset:32\n\t"
                "ds_read_b128 v[96:99], v80 offset:48\n\t"
                "ds_read_b128 v[100:103], v80 offset:64\n\t"
                "ds_read_b128 v[104:107], v80 offset:80\n\t"
                "ds_read_b128 v[108:111], v80 offset:96\n\t"
                "ds_read_b128 v[112:115], v80 offset:112\n\t"
                "v_add_u32 v80, 128, v80\n\t"
                "s_waitcnt lgkmcnt(4)\n\t"
                GLD("v84", "v132") GLD("v85", "v133")
                GLD("v86", "v134") GLD("v87", "v135")
                GLD("v88", "v136") GLD("v89", "v137")
                GLD("v90", "v138") GLD("v91", "v139")
                GLD("v92", "v140") GLD("v93", "v141")
                GLD("v94", "v142") GLD("v95", "v143")
                GLD("v96", "v144") GLD("v97", "v145")
                GLD("v98", "v146") GLD("v99", "v147")
                "s_waitcnt vmcnt(16)\n\t"
                ADDF("v116") ADDF("v117") ADDF("v118") ADDF("v119")
                ADDF("v120") ADDF("v121") ADDF("v122") ADDF("v123")
                ADDF("v124") ADDF("v125") ADDF("v126") ADDF("v127")
                ADDF("v128") ADDF("v129") ADDF("v130") ADDF("v131")
                "s_waitcnt lgkmcnt(0)\n\t"
                GLD("v100", "v116") GLD("v101", "v117")
                GLD("v102", "v118") GLD("v103", "v119")
                GLD("v104", "v120") GLD("v105", "v121")
                GLD("v106", "v122") GLD("v107", "v123")
                GLD("v108", "v124") GLD("v109", "v125")
                GLD("v110", "v126") GLD("v111", "v127")
                GLD("v112", "v128") GLD("v113", "v129")
                GLD("v114", "v130") GLD("v115", "v131")
                "s_waitcnt vmcnt(16)\n\t"
                ADDF("v132") ADDF("v133") ADDF("v134") ADDF("v135")
                ADDF("v136") ADDF("v137") ADDF("v138") ADDF("v139")
                ADDF("v140") ADDF("v141") ADDF("v142") ADDF("v143")
                ADDF("v144") ADDF("v145") ADDF("v146") ADDF("v147")
                "v_subrev_u32 v81, 32, v81\n\t"
                "v_cmp_lt_i32 vcc, 0, v81\n\t"
                "s_cbranch_vccnz Lg%=\n\t"
                "s_waitcnt vmcnt(0)\n\t"
                : [rec] "+v"(rec)
                : [lds] "v"(lds_off), [cnt] "v"(cnt), [n4] "v"(n4),
                  [wb] "s"(wb)
                : "v80", "v81", "v82",
                  "v84", "v85", "v86", "v87", "v88", "v89", "v90", "v91",
                  "v92", "v93", "v94", "v95", "v96", "v97", "v98", "v99",
                  "v100", "v101", "v102", "v103", "v104", "v105", "v106", "v107",
                  "v108", "v109", "v110", "v111", "v112", "v113", "v114", "v115",
                  "v116", "v117", "v118", "v119", "v120", "v121", "v122", "v123",
                  "v124", "v125", "v126", "v127", "v128", "v129", "v130", "v131",
                  "v132", "v133", "v134", "v135", "v136", "v137", "v138", "v139",
                  "v140", "v141", "v142", "v143", "v144", "v145", "v146", "v147",
                  "vcc", "memory");
        }

        op[0] = zn;
        op += (size_t)BB * NH;
        cur = __fadd_rn(__fadd_rn(i_dec, fval), rec);
        zprev = zn;

        __syncthreads();   // B1: cnts[par^1] published; lists[par] drained

        // ---- t.3: build next list (lists[par^1]) ----------------------------
        int base = 0, tot = 0;
        for (int q = 0; q < 8; ++q) {
            const int c = cnts[par ^ 1][q];
            if (q < wv) base += c;
            tot += c;
        }
        if (zn > 0.0f)
            lists[par ^ 1][base + __popcll(mm & ((1ull << lane) - 1ull))] = n << 11;
        if (n < LPAD) lists[par ^ 1][tot + n] = PADOFF;
        __syncthreads();   // B2: lists[par^1] ready

        par ^= 1;
        cnt = tot;
    }

    st[0 * BB * NH + bn] = zprev;
    st[1 * BB * NH + bn] = v;
    st[2 * BB * NH + bn] = cur;
    st[3 * BB * NH + bn] = bb;
    if (last) {
        float* tail = out + (size_t)TT * BB * NH;
        tail[0 * BB * NH + bn] = zprev;  // zT
        tail[1 * BB * NH + bn] = v;      // vT
        tail[2 * BB * NH + bn] = cur;    // iT
        tail[3 * BB * NH + bn] = bb;     // bT
    }
}

// ---------------------------------------------------------------------------
extern "C" void kernel_launch(void* const* d_in, const int* in_sizes, int n_in,
                              void* d_out, int out_size, void* d_ws, size_t ws_size,
                              hipStream_t stream) {
    const float* X     = (const float*)d_in[0];
    const float* z0    = (const float*)d_in[1];
    const float* v0    = (const float*)d_in[2];
    const float* i0    = (const float*)d_in[3];
    const float* b0    = (const float*)d_in[4];
    const float* w_in  = (const float*)d_in[5];
    const float* w_rec = (const float*)d_in[6];
    float* out = (float*)d_out;

    char* ws = (char*)d_ws;
    float* wT = (float*)ws;                                    // 1 MB + zero row
    const size_t wT_bytes = ((size_t)NH * NH + NH) * 4 + 2048;
    float* st = (float*)(ws + wT_bytes);                       // 512 KB
    char*  fbase = ws + wT_bytes + (512u << 10);

    const long long per = (long long)BB * NH * 4;              // bytes/step of F
    long long avail = (long long)ws_size - (long long)(wT_bytes + (512u << 10));
    int Tc;
    if (avail >= 2 * per * TT) {
        Tc = TT;
    } else {
        Tc = (int)(avail / (2 * per));
        if (Tc > TT) Tc = TT;
        Tc &= ~1;
        if (Tc < 2) Tc = 2;
    }
    const size_t fbytes = (size_t)Tc * per;
    float* Fb[2] = { (float*)fbase, (float*)(fbase + fbytes) };

    transp512<<<dim3(16, 16), dim3(32, 8), 0, stream>>>(w_rec, wT);
    zrow<<<1, NH, 0, stream>>>(wT);

    int t0 = 0, buf = 0;
    bool firstc = true;
    while (t0 < TT) {
        const int Tcur = (Tc < TT - t0) ? Tc : (TT - t0);
        const int Mc = Tcur * BB;
        gemm_ff<<<dim3(4, Mc / 128), 256, 0, stream>>>(
            X + (size_t)t0 * BB * NIN, w_in, Fb[buf], Mc);
        lsnn_scan<<<dim3(BB), dim3(512), 0, stream>>>(
            Fb[buf], wT, z0, v0, i0, b0, out, st,
            t0, Tcur, firstc ? 1 : 0, (t0 + Tcur >= TT) ? 1 : 0);
        firstc = false;
        buf ^= 1;
        t0 += Tcur;
    }
}

// Round 6
// 2827.800 us; speedup vs baseline: 1.0425x; 1.0290x over previous
//
#include <hip/hip_runtime.h>
#include <hip/hip_bf16.h>

// LSNN adaptive-LIF scan, T=1000, B=64, N_in=256, N_h=512, fp32.
//
// BITWISE CONSTRAINT (rounds 2-5): harness compares binary spikes exactly;
// flips cascade. The recurrent term for column n MUST be one serial
// ascending-index __fadd_rn chain over active neurons. No partial sums.
// Pad rows (+0.0 from zeroed row 512) are bitwise neutral. absmax 0 across
// all passing rounds.
//
// Round 13: r12 (raw asm, guaranteed 32 loads in flight, counted vmcnt)
// timed IDENTICAL to r7's compiler code -> in-flight depth, latency
// distance, and scheduling are all experimentally excluded. Surviving
// model: per-CU memory-port throughput wall (~60 B/cy L1/TCP ingest).
// Gather = cnt x 2KB per step through ONE CU per batch = cnt*2048/62 =
// ~5900 cy/step = the measured invariant. r11's 4-way split failed to show
// this because its compiler-rolled gather (4-deep) on 1 wave/SIMD exposed
// cnt/4 x 250cy of latency, masking the port gain. This round: 2-way
// column split (128 WGs x 256 thr, 4 waves) -> per-CU gather bytes /2,
// WITH the r12 asm gather (32-deep, latency stays hidden: 2 waves x 32
// x 256B = 16KB in flight >= BW*latency ~13KB). Cross-WG mask exchange =
// r11's proven tagged-atomic protocol (hi32 = step code, lo32 = half-mask,
// relaxed agent scope, RING=4, skew bound <= 2 steps). Poll fills all 16
// half-masks (own included, published one step earlier) -> no separate
// own-mask path, single list buffer. LPAD=96 (asm reads offsets to
// cnt+78; r12's LPAD=64 over-read benign garbage -- now padded properly).

#define TT   1000
#define BB   64
#define NIN  256
#define NH   512
#define LPAD 96                          // asm reads offsets up to cnt+78
#define PADOFF (NH * 2048)               // byte offset of zeroed row 512 of wT
#define NW   2                           // WGs per batch (column split)
#define WCOLS (NH / NW)                  // 256 columns per WG
#define RING 4                           // mask ring slots

__device__ constexpr float KV = (float)(0.001 * 100.0);            // DT*TAU_MEM_INV
__device__ constexpr float KI = (float)(0.001 * 200.0);            // DT*TAU_SYN_INV
__device__ constexpr float KB = (float)(0.001 * (1.0 / 800.0));    // DT*TAU_ADAPT_INV
__device__ constexpr float KJ = (float)((1.0 / 800.0) * 1.8);      // TAU_ADAPT_INV*BETA

// ---------------- transpose w_rec (512x512): wT[j][n] = w_rec[n][j] ----------
__global__ void transp512(const float* __restrict__ in, float* __restrict__ ot) {
    __shared__ float tile[32][33];
    const int tx = threadIdx.x;            // 0..31
    const int ty = threadIdx.y;            // 0..7
    const int jcol = blockIdx.x * 32 + tx;
    const int row0 = blockIdx.y * 32;
    for (int r = ty; r < 32; r += 8)
        tile[r][tx] = in[(size_t)(row0 + r) * NH + jcol];
    __syncthreads();
    const int ncol = blockIdx.y * 32 + tx;
    const int jrow0 = blockIdx.x * 32;
    for (int r = ty; r < 32; r += 8)
        ot[(size_t)(jrow0 + r) * NH + ncol] = tile[tx][r];
}

// zero row 512 of wT (padding target for unconditional gather tiles)
__global__ void zrow(float* __restrict__ wT) {
    wT[(size_t)NH * NH + threadIdx.x] = 0.0f;
}

// zero the mask ring (tag 0 = invalid; published codes are >= 1)
__global__ void zmask(unsigned long long* __restrict__ gm) {
    for (int k = threadIdx.x; k < RING * BB * 16; k += 256) gm[k] = 0ull;
}

// ---------------- fp32 GEMM: F[m][n] = sum_k X[m][k] * W[n][k] ---------------
// UNCHANGED from round 2 (bitwise-verified against the np reference).
__global__ __launch_bounds__(256)
void gemm_ff(const float* __restrict__ X, const float* __restrict__ W,
             float* __restrict__ F, int M) {
    const int bx = blockIdx.x;   // n-tile: 0..3
    const int by = blockIdx.y;   // m-tile
    const int tid = threadIdx.x;

    __shared__ float As[32][128];
    __shared__ float Bs[32][128];

    const int tn0 = (tid & 15) * 8;
    const int tm0 = (tid >> 4) * 8;
    float acc[8][8] = {};

    const int am = tid >> 1;
    const int aq = (tid & 1) * 4;

    const float* Xb = X + (size_t)(by * 128 + am) * NIN;
    const float* Wb = W + (size_t)(bx * 128 + am) * NIN;

    for (int k0 = 0; k0 < NIN; k0 += 32) {
        __syncthreads();
#pragma unroll
        for (int i2 = 0; i2 < 4; ++i2) {
            const int q = aq + i2;
            float4 xa = *reinterpret_cast<const float4*>(Xb + k0 + q * 4);
            As[q * 4 + 0][am] = xa.x; As[q * 4 + 1][am] = xa.y;
            As[q * 4 + 2][am] = xa.z; As[q * 4 + 3][am] = xa.w;
            float4 wa = *reinterpret_cast<const float4*>(Wb + k0 + q * 4);
            Bs[q * 4 + 0][am] = wa.x; Bs[q * 4 + 1][am] = wa.y;
            Bs[q * 4 + 2][am] = wa.z; Bs[q * 4 + 3][am] = wa.w;
        }
        __syncthreads();
#pragma unroll 8
        for (int kk = 0; kk < 32; ++kk) {
            float4 a0 = *reinterpret_cast<const float4*>(&As[kk][tm0]);
            float4 a1 = *reinterpret_cast<const float4*>(&As[kk][tm0 + 4]);
            float4 b0 = *reinterpret_cast<const float4*>(&Bs[kk][tn0]);
            float4 b1 = *reinterpret_cast<const float4*>(&Bs[kk][tn0 + 4]);
            const float av[8] = {a0.x, a0.y, a0.z, a0.w, a1.x, a1.y, a1.z, a1.w};
            const float bv[8] = {b0.x, b0.y, b0.z, b0.w, b1.x, b1.y, b1.z, b1.w};
#pragma unroll
            for (int i = 0; i < 8; ++i)
#pragma unroll
                for (int j = 0; j < 8; ++j)
                    acc[i][j] += av[i] * bv[j];
        }
    }

    float* Fo = F + (size_t)(by * 128 + tm0) * NH + bx * 128 + tn0;
#pragma unroll
    for (int i = 0; i < 8; ++i) {
        *reinterpret_cast<float4*>(Fo + (size_t)i * NH) =
            make_float4(acc[i][0], acc[i][1], acc[i][2], acc[i][3]);
        *reinterpret_cast<float4*>(Fo + (size_t)i * NH + 4) =
            make_float4(acc[i][4], acc[i][5], acc[i][6], acc[i][7]);
    }
}

// ---------------- asm gather building blocks (UNCHANGED from r12) ------------
#define GLD(o, d) \
    "v_add_u32 v82, %[n4], " o "\n\t" \
    "global_load_dword " d ", v82, %[wb]\n\t"
#define ADDF(s) "v_add_f32 %[rec], %[rec], " s "\n\t"

// ---------------- scan kernel: 2 WGs x 256 threads per batch ----------------
// blockIdx = b + 64*s. st layout: [z | v | i | b], each BB*NH floats.
// gmask word index = ((slot*BB + b)*16) + s*8 + wv*2 + half; word =
// (code << 32) | mask32 where code = fed_step + 1.
__global__ __launch_bounds__(WCOLS, 1)
void lsnn_scan(const float* __restrict__ F, const float* __restrict__ wT,
               const float* __restrict__ z0, const float* __restrict__ v0,
               const float* __restrict__ i0, const float* __restrict__ b0,
               float* __restrict__ out, float* __restrict__ st,
               unsigned long long* __restrict__ gmask,
               int t0, int Tc, int first, int last) {
    const int tid  = threadIdx.x;              // 0..255
    const int b    = blockIdx.x & (BB - 1);    // batch
    const int s    = blockIdx.x >> 6;          // column half 0..1
    const int lane = tid & 63;
    const int wv   = tid >> 6;                 // wave 0..3
    const int c    = s * WCOLS + tid;          // global column
    const size_t bn = (size_t)b * NH + c;

    __shared__ __align__(16) int list_[NH + LPAD];
    __shared__ unsigned smask32[16];

    float v, cur, bb, zprev;
    if (first) {
        zprev = z0[bn]; v = v0[bn]; cur = i0[bn]; bb = b0[bn];
    } else {
        zprev = st[0 * BB * NH + bn];
        v     = st[1 * BB * NH + bn];
        cur   = st[2 * BB * NH + bn];
        bb    = st[3 * BB * NH + bn];
    }

    // ---- entry publish: zprev half-masks, code t0+1 (feeds step t0) --------
    {
        const unsigned long long m0 = __ballot(zprev > 0.0f);
        if (lane == 0) {
            const size_t gi = (((size_t)((unsigned)t0 & (RING - 1)) * BB + b) << 4)
                              + (unsigned)(s * 8 + wv * 2);
            const unsigned long long code = (unsigned long long)(unsigned)(t0 + 1) << 32;
            __hip_atomic_store(&gmask[gi],     code | (unsigned)(m0 & 0xffffffffull),
                               __ATOMIC_RELAXED, __HIP_MEMORY_SCOPE_AGENT);
            __hip_atomic_store(&gmask[gi + 1], code | (unsigned)(m0 >> 32),
                               __ATOMIC_RELAXED, __HIP_MEMORY_SCOPE_AGENT);
        }
    }

    const char*  wb = reinterpret_cast<const char*>(wT);   // uniform base (SGPR)
    const unsigned n4 = (unsigned)c * 4u;                  // column byte offset
    const float* Fp = F + (size_t)b * NH + c;
    float* op = out + ((size_t)t0 * BB + b) * NH + c;

    for (int t = 0; t < Tc; ++t) {
        const unsigned T = (unsigned)(t0 + t);

        // ---- A: elementwise update, ballot, publish next mask ---------------
        const float v_dec = __fadd_rn(v, __fmul_rn(KV, __fadd_rn(__fsub_rn(0.0f, v), cur)));
        const float i_dec = __fsub_rn(cur, __fmul_rn(KI, cur));
        const float b_dec = __fadd_rn(bb, __fmul_rn(KB, __fsub_rn(1.0f, bb)));
        const float zn = (__fsub_rn(v_dec, b_dec) > 0.0f) ? 1.0f : 0.0f;
        v  = (zn > 0.0f) ? 0.0f : v_dec;
        bb = __fadd_rn(b_dec, __fmul_rn(zn, KJ));
        const unsigned long long mm = __ballot(zn > 0.0f);
        if (lane == 0) {
            // mask feeding step T+1 -> code T+2, slot (T+1)&3
            const size_t gi = (((size_t)((T + 1u) & (RING - 1)) * BB + b) << 4)
                              + (unsigned)(s * 8 + wv * 2);
            const unsigned long long code = (unsigned long long)(T + 2u) << 32;
            __hip_atomic_store(&gmask[gi],     code | (unsigned)(mm & 0xffffffffull),
                               __ATOMIC_RELAXED, __HIP_MEMORY_SCOPE_AGENT);
            __hip_atomic_store(&gmask[gi + 1], code | (unsigned)(mm >> 32),
                               __ATOMIC_RELAXED, __HIP_MEMORY_SCOPE_AGENT);
        }

        // ---- C: acquire all 16 half-masks feeding step T (code T+1) --------
        // Own half was published one step earlier (or at entry) -> poll all.
        if (tid < 16) {
            const size_t gi = (((size_t)(T & (RING - 1)) * BB + b) << 4) + tid;
            unsigned long long x;
            do {
                x = __hip_atomic_load(&gmask[gi], __ATOMIC_RELAXED,
                                      __HIP_MEMORY_SCOPE_AGENT);
            } while ((unsigned)(x >> 32) != T + 1u);
            smask32[tid] = (unsigned)x;
        }
        __syncthreads();   // D: masks in LDS; also fences last step's gather

        // ---- E: build ascending row-offset list (all 512 rows) --------------
        unsigned long long w8[8];
        int bases[8];
        int run = 0;
#pragma unroll
        for (int w = 0; w < 8; ++w) {
            w8[w] = (unsigned long long)smask32[2 * w]
                  | ((unsigned long long)smask32[2 * w + 1] << 32);
            bases[w] = run;
            run += __popcll(w8[w]);
        }
        const int cnt = run;
#pragma unroll
        for (int q = 0; q < 2; ++q) {           // 256 threads scatter 512 bits
            const int m_ = q * WCOLS + tid;
            const int w = m_ >> 6;
            const int bit = m_ & 63;
            const unsigned long long m = w8[w];
            if ((m >> bit) & 1ull)
                list_[bases[w] + __popcll(m & ((1ull << bit) - 1ull))] = m_ << 11;
        }
        if (tid < LPAD) list_[cnt + tid] = PADOFF;
        __syncthreads();   // Fb: list ready

        // ---- G: out store + F prefetch + asm gather (r12, unchanged) -------
        op[0] = zn;
        op += (size_t)BB * NH;
        const float fval = Fp[(size_t)t * BB * NH];   // hidden under gather

        float rec = 0.0f;
        if (cnt > 0) {
            const unsigned lds_off =
                (unsigned)(unsigned long long)(const void*)list_;
            asm volatile(
                "v_mov_b32 v80, %[lds]\n\t"
                "v_mov_b32 v81, %[cnt]\n\t"
                "ds_read_b128 v[84:87], v80\n\t"
                "ds_read_b128 v[88:91], v80 offset:16\n\t"
                "ds_read_b128 v[92:95], v80 offset:32\n\t"
                "ds_read_b128 v[96:99], v80 offset:48\n\t"
                "v_add_u32 v80, 64, v80\n\t"
                "s_waitcnt lgkmcnt(0)\n\t"
                GLD("v84", "v116") GLD("v85", "v117")
                GLD("v86", "v118") GLD("v87", "v119")
                GLD("v88", "v120") GLD("v89", "v121")
                GLD("v90", "v122") GLD("v91", "v123")
                GLD("v92", "v124") GLD("v93", "v125")
                GLD("v94", "v126") GLD("v95", "v127")
                GLD("v96", "v128") GLD("v97", "v129")
                GLD("v98", "v130") GLD("v99", "v131")
                "Lg%=:\n\t"
                "ds_read_b128 v[84:87], v80\n\t"
                "ds_read_b128 v[88:91], v80 offset:16\n\t"
                "ds_read_b128 v[92:95], v80 offset:32\n\t"
                "ds_read_b128 v[96:99], v80 offset:48\n\t"
                "ds_read_b128 v[100:103], v80 offset:64\n\t"
                "ds_read_b128 v[104:107], v80 offset:80\n\t"
                "ds_read_b128 v[108:111], v80 offset:96\n\t"
                "ds_read_b128 v[112:115], v80 offset:112\n\t"
                "v_add_u32 v80, 128, v80\n\t"
                "s_waitcnt lgkmcnt(4)\n\t"
                GLD("v84", "v132") GLD("v85", "v133")
                GLD("v86", "v134") GLD("v87", "v135")
                GLD("v88", "v136") GLD("v89", "v137")
                GLD("v90", "v138") GLD("v91", "v139")
                GLD("v92", "v140") GLD("v93", "v141")
                GLD("v94", "v142") GLD("v95", "v143")
                GLD("v96", "v144") GLD("v97", "v145")
                GLD("v98", "v146") GLD("v99", "v147")
                "s_waitcnt vmcnt(16)\n\t"
                ADDF("v116") ADDF("v117") ADDF("v118") ADDF("v119")
                ADDF("v120") ADDF("v121") ADDF("v122") ADDF("v123")
                ADDF("v124") ADDF("v125") ADDF("v126") ADDF("v127")
                ADDF("v128") ADDF("v129") ADDF("v130") ADDF("v131")
                "s_waitcnt lgkmcnt(0)\n\t"
                GLD("v100", "v116") GLD("v101", "v117")
                GLD("v102", "v118") GLD("v103", "v119")
                GLD("v104", "v120") GLD("v105", "v121")
                GLD("v106", "v122") GLD("v107", "v123")
                GLD("v108", "v124") GLD("v109", "v125")
                GLD("v110", "v126") GLD("v111", "v127")
                GLD("v112", "v128") GLD("v113", "v129")
                GLD("v114", "v130") GLD("v115", "v131")
                "s_waitcnt vmcnt(16)\n\t"
                ADDF("v132") ADDF("v133") ADDF("v134") ADDF("v135")
                ADDF("v136") ADDF("v137") ADDF("v138") ADDF("v139")
                ADDF("v140") ADDF("v141") ADDF("v142") ADDF("v143")
                ADDF("v144") ADDF("v145") ADDF("v146") ADDF("v147")
                "v_subrev_u32 v81, 32, v81\n\t"
                "v_cmp_lt_i32 vcc, 0, v81\n\t"
                "s_cbranch_vccnz Lg%=\n\t"
                "s_waitcnt vmcnt(0)\n\t"
                : [rec] "+v"(rec)
                : [lds] "v"(lds_off), [cnt] "v"(cnt), [n4] "v"(n4),
                  [wb] "s"(wb)
                : "v80", "v81", "v82",
                  "v84", "v85", "v86", "v87", "v88", "v89", "v90", "v91",
                  "v92", "v93", "v94", "v95", "v96", "v97", "v98", "v99",
                  "v100", "v101", "v102", "v103", "v104", "v105", "v106", "v107",
                  "v108", "v109", "v110", "v111", "v112", "v113", "v114", "v115",
                  "v116", "v117", "v118", "v119", "v120", "v121", "v122", "v123",
                  "v124", "v125", "v126", "v127", "v128", "v129", "v130", "v131",
                  "v132", "v133", "v134", "v135", "v136", "v137", "v138", "v139",
                  "v140", "v141", "v142", "v143", "v144", "v145", "v146", "v147",
                  "vcc", "memory");
        }

        cur = __fadd_rn(__fadd_rn(i_dec, fval), rec);
        zprev = zn;
    }

    st[0 * BB * NH + bn] = zprev;
    st[1 * BB * NH + bn] = v;
    st[2 * BB * NH + bn] = cur;
    st[3 * BB * NH + bn] = bb;
    if (last) {
        float* tail = out + (size_t)TT * BB * NH;
        tail[0 * BB * NH + bn] = zprev;  // zT
        tail[1 * BB * NH + bn] = v;      // vT
        tail[2 * BB * NH + bn] = cur;    // iT
        tail[3 * BB * NH + bn] = bb;     // bT
    }
}

// ---------------------------------------------------------------------------
extern "C" void kernel_launch(void* const* d_in, const int* in_sizes, int n_in,
                              void* d_out, int out_size, void* d_ws, size_t ws_size,
                              hipStream_t stream) {
    const float* X     = (const float*)d_in[0];
    const float* z0    = (const float*)d_in[1];
    const float* v0    = (const float*)d_in[2];
    const float* i0    = (const float*)d_in[3];
    const float* b0    = (const float*)d_in[4];
    const float* w_in  = (const float*)d_in[5];
    const float* w_rec = (const float*)d_in[6];
    float* out = (float*)d_out;

    char* ws = (char*)d_ws;
    float* wT = (float*)ws;                                    // 1 MB + zero row
    const size_t wT_bytes = ((size_t)NH * NH + NH) * 4 + 2048;
    float* st = (float*)(ws + wT_bytes);                       // 512 KB
    const size_t mask_bytes = (size_t)RING * BB * 16 * 8;      // 32 KB
    unsigned long long* gmask =
        (unsigned long long*)(ws + wT_bytes + (512u << 10));
    char* fbase = ws + wT_bytes + (512u << 10) + mask_bytes;

    const long long per = (long long)BB * NH * 4;              // bytes/step of F
    long long avail = (long long)ws_size
                    - (long long)(wT_bytes + (512u << 10) + mask_bytes);
    int Tc;
    if (avail >= 2 * per * TT) {
        Tc = TT;
    } else {
        Tc = (int)(avail / (2 * per));
        if (Tc > TT) Tc = TT;
        Tc &= ~1;
        if (Tc < 2) Tc = 2;
    }
    const size_t fbytes = (size_t)Tc * per;
    float* Fb[2] = { (float*)fbase, (float*)(fbase + fbytes) };

    transp512<<<dim3(16, 16), dim3(32, 8), 0, stream>>>(w_rec, wT);
    zrow<<<1, NH, 0, stream>>>(wT);
    zmask<<<1, 256, 0, stream>>>(gmask);

    int t0 = 0, buf = 0;
    bool firstc = true;
    while (t0 < TT) {
        const int Tcur = (Tc < TT - t0) ? Tc : (TT - t0);
        const int Mc = Tcur * BB;
        gemm_ff<<<dim3(4, Mc / 128), 256, 0, stream>>>(
            X + (size_t)t0 * BB * NIN, w_in, Fb[buf], Mc);
        lsnn_scan<<<dim3(BB * NW), dim3(WCOLS), 0, stream>>>(
            Fb[buf], wT, z0, v0, i0, b0, out, st, gmask,
            t0, Tcur, firstc ? 1 : 0, (t0 + Tcur >= TT) ? 1 : 0);
        firstc = false;
        buf ^= 1;
        t0 += Tcur;
    }
}